// Round 9
// baseline (176.203 us; speedup 1.0000x reference)
//
#include <hip/hip_runtime.h>

#define L_SEQ 2048
#define NH    16
#define E_DIM 1024
#define M_ROWS 4096

typedef unsigned short u16;
typedef unsigned int   u32;
typedef __attribute__((ext_vector_type(8))) __bf16 bf16x8;
typedef __attribute__((ext_vector_type(4))) float  f32x4;

__device__ __forceinline__ u16 f2bf(float f) {
  union { float f; u32 u; } x; x.f = f;
  u32 u = x.u;
  return (u16)((u + 0x7FFFu + ((u >> 16) & 1u)) >> 16);
}
__device__ __forceinline__ float bf2f(u16 v) {
  union { u32 u; float f; } x; x.u = ((u32)v) << 16;
  return x.f;
}
__device__ __forceinline__ void st_bf4(u16* p, float a, float b, float c, float d) {
  ushort4 u; u.x = f2bf(a); u.y = f2bf(b); u.z = f2bf(c); u.w = f2bf(d);
  *reinterpret_cast<ushort4*>(p) = u;
}
// async global->LDS, 16B per lane; LDS dest must be linear in lane order
__device__ __forceinline__ void gload16(const u16* g, u16* l) {
  __builtin_amdgcn_global_load_lds(
      (const __attribute__((address_space(1))) void*)g,
      (__attribute__((address_space(3))) void*)l, 16, 0, 0);
}
#define SBAR() asm volatile("s_barrier" ::: "memory")

// ---------------- LayerNorm x-hat only (g/b folded into weights/bias): fp32 in -> bf16 out ----------------
__global__ __launch_bounds__(256) void ln_hat_f32(const float* __restrict__ x, u16* __restrict__ o)
{
  __shared__ float red[8];
  const size_t row = blockIdx.x;
  const int t = threadIdx.x;
  float4 v = reinterpret_cast<const float4*>(x + row * E_DIM)[t];
  float s = v.x + v.y + v.z + v.w;
  float q = v.x*v.x + v.y*v.y + v.z*v.z + v.w*v.w;
  #pragma unroll
  for (int off = 32; off; off >>= 1) { s += __shfl_down(s, off); q += __shfl_down(q, off); }
  if ((t & 63) == 0) { red[t >> 6] = s; red[4 + (t >> 6)] = q; }
  __syncthreads();
  float S = red[0] + red[1] + red[2] + red[3];
  float Q = red[4] + red[5] + red[6] + red[7];
  float mean = S * (1.f / E_DIM);
  float rstd = rsqrtf(Q * (1.f / E_DIM) - mean * mean + 1e-5f);
  st_bf4(o + row * E_DIM + t * 4,
         (v.x - mean) * rstd, (v.y - mean) * rstd, (v.z - mean) * rstd, (v.w - mean) * rstd);
}

// ---------------- LayerNorm x-hat only: bf16 in -> bf16 out ----------------
__global__ __launch_bounds__(256) void ln_hat_bf16(const u16* __restrict__ x, u16* __restrict__ o)
{
  __shared__ float red[8];
  const size_t row = blockIdx.x;
  const int t = threadIdx.x;
  ushort4 u = reinterpret_cast<const ushort4*>(x + row * E_DIM)[t];
  float v0 = bf2f(u.x), v1 = bf2f(u.y), v2 = bf2f(u.z), v3 = bf2f(u.w);
  float s = v0 + v1 + v2 + v3;
  float q = v0*v0 + v1*v1 + v2*v2 + v3*v3;
  #pragma unroll
  for (int off = 32; off; off >>= 1) { s += __shfl_down(s, off); q += __shfl_down(q, off); }
  if ((t & 63) == 0) { red[t >> 6] = s; red[4 + (t >> 6)] = q; }
  __syncthreads();
  float S = red[0] + red[1] + red[2] + red[3];
  float Q = red[4] + red[5] + red[6] + red[7];
  float mean = S * (1.f / E_DIM);
  float rstd = rsqrtf(Q * (1.f / E_DIM) - mean * mean + 1e-5f);
  st_bf4(o + row * E_DIM + t * 4,
         (v0 - mean) * rstd, (v1 - mean) * rstd, (v2 - mean) * rstd, (v3 - mean) * rstd);
}

// ---------------- fused weight transposes + LN-gamma fold: WT[n,e] = bf16(W[e,n] * g[e]) ----------------
__global__ __launch_bounds__(256) void transpose_all(
    const float* __restrict__ W0, const float* __restrict__ W1,
    const float* __restrict__ W2, const float* __restrict__ W3,
    const float* __restrict__ g0, const float* __restrict__ g1,
    const float* __restrict__ g2, const float* __restrict__ g3,
    u16* __restrict__ T0, u16* __restrict__ T1, u16* __restrict__ T2, u16* __restrict__ T3)
{
  __shared__ float tile[32][33];
  const int z = blockIdx.z;
  const float* W = (z == 0) ? W0 : (z == 1) ? W1 : (z == 2) ? W2 : W3;
  const float* g = (z == 0) ? g0 : (z == 1) ? g1 : (z == 2) ? g2 : g3;
  u16* T = (z == 0) ? T0 : (z == 1) ? T1 : (z == 2) ? T2 : T3;
  const int tx = threadIdx.x & 31, ty = threadIdx.x >> 5;
  const int bx = blockIdx.x * 32, by = blockIdx.y * 32;
  #pragma unroll
  for (int r = 0; r < 4; ++r) {
    const int e = by + ty + r * 8;
    tile[ty + r * 8][tx] = W[(size_t)e * E_DIM + bx + tx] * g[e];
  }
  __syncthreads();
  #pragma unroll
  for (int r = 0; r < 4; ++r)
    T[(size_t)(bx + ty + r * 8) * E_DIM + by + tx] = f2bf(tile[tx][ty + r * 8]);
}

// ---------------- bias fold (parallel): bfold[z][n] = bias_z[n] + sum_e bln_z[e] * W_z[e,n] ----------------
__global__ __launch_bounds__(256) void bias_fold(
    const float* __restrict__ W0, const float* __restrict__ W1,
    const float* __restrict__ W2, const float* __restrict__ W3,
    const float* __restrict__ l0, const float* __restrict__ l1,
    const float* __restrict__ l2, const float* __restrict__ l3,
    const float* __restrict__ b0, const float* __restrict__ b1,
    const float* __restrict__ b2, const float* __restrict__ b3,
    float* __restrict__ bfold)
{
  __shared__ float part[8][32];
  const int z = blockIdx.y;
  const float* W  = (z == 0) ? W0 : (z == 1) ? W1 : (z == 2) ? W2 : W3;
  const float* bl = (z == 0) ? l0 : (z == 1) ? l1 : (z == 2) ? l2 : l3;
  const float* bs = (z == 0) ? b0 : (z == 1) ? b1 : (z == 2) ? b2 : b3;
  const int tn = threadIdx.x & 31, te = threadIdx.x >> 5;
  const int n = blockIdx.x * 32 + tn;
  float acc = 0.f;
  const int e0 = te * 128;
  for (int e = e0; e < e0 + 128; ++e) acc += bl[e] * W[(size_t)e * E_DIM + n];
  part[te][tn] = acc;
  __syncthreads();
  if (te == 0) {
    float s = part[0][tn] + part[1][tn] + part[2][tn] + part[3][tn]
            + part[4][tn] + part[5][tn] + part[6][tn] + part[7][tn];
    bfold[z * E_DIM + n] = bs[n] + s;
  }
}

// ---------------- 128x128 counted-vmcnt GEMM core, BK=32, 4 waves, 32 KB LDS ----------------
// m97 geometry (3 blocks/CU co-resident) + counted-vmcnt dbuf. BK=32 rows are 64B
// -> lane spread (4fr+hi)%8 uniform -> linear LDS, no swizzle needed.
// Discipline: [bar: done reading buf^1] -> STAGE(kt+1 into buf^1) -> vmcnt(4):
// own kt loads done -> [bar: ALL waves' kt loads landed] -> PHASES(kt).
#define GBK 32
__device__ __forceinline__ void core128(
    const u16* __restrict__ A, const u16* __restrict__ BT,
    int m0, int n0, int t, u16* lds, f32x4 (&acc)[4][4])
{
  const int lane = t & 63, wave = t >> 6;
  const int wm = wave >> 1, wn = wave & 1;
  const int fr = lane & 15, hi = lane >> 4;

  auto STAGE = [&](int buf, int kt) {
    u16* la = lds + (buf * 2 + 0) * (128 * GBK);
    u16* lb = lds + (buf * 2 + 1) * (128 * GBK);
    #pragma unroll
    for (int s = 0; s < 2; ++s) {
      const int seg = t + s * 256;
      const int r = seg >> 2, c8 = (seg & 3) * 8;
      gload16(A + (size_t)(m0 + r) * E_DIM + kt * GBK + c8, la + seg * 8);
    }
    #pragma unroll
    for (int s = 0; s < 2; ++s) {
      const int seg = t + s * 256;
      const int r = seg >> 2, c8 = (seg & 3) * 8;
      gload16(BT + (size_t)(n0 + r) * E_DIM + kt * GBK + c8, lb + seg * 8);
    }
  };
  auto PHASES = [&](int buf) {
    const u16* la = lds + (buf * 2 + 0) * (128 * GBK);
    const u16* lb = lds + (buf * 2 + 1) * (128 * GBK);
    bf16x8 a[4], b[4];
    #pragma unroll
    for (int i = 0; i < 4; ++i)
      a[i] = *reinterpret_cast<const bf16x8*>(&la[(wm * 64 + i * 16 + fr) * GBK + hi * 8]);
    #pragma unroll
    for (int j = 0; j < 4; ++j)
      b[j] = *reinterpret_cast<const bf16x8*>(&lb[(wn * 64 + j * 16 + fr) * GBK + hi * 8]);
    __builtin_amdgcn_s_setprio(1);
    #pragma unroll
    for (int i = 0; i < 4; ++i)
      #pragma unroll
      for (int j = 0; j < 4; ++j)
        acc[i][j] = __builtin_amdgcn_mfma_f32_16x16x32_bf16(a[i], b[j], acc[i][j], 0, 0, 0);
    __builtin_amdgcn_s_setprio(0);
  };

  STAGE(0, 0);                                      // prologue: kt0's 4 loads in flight
  #pragma unroll 1
  for (int kt = 0; kt < 31; ++kt) {
    const int buf = kt & 1;
    SBAR();                                         // all waves done reading buf^1 (kt-1)
    STAGE(buf ^ 1, kt + 1);                         // kt+1's 4 loads: stay in flight
    asm volatile("s_waitcnt vmcnt(4)" ::: "memory");// own kt loads done
    SBAR();                                         // => ALL waves' kt loads landed
    PHASES(buf);
  }
  asm volatile("s_waitcnt vmcnt(0)" ::: "memory");  // peeled last K-tile (kt=31, buf=1)
  SBAR();
  PHASES(1);
}

// ---------------- fused QKV GEMM: 768 blocks (32m x 24n), z = n0>>10 ----------------
// z=0 q(bf16), z=1 k(fp32 T + bf16), z=2 v(fp32 + bf16 T)
__global__ __launch_bounds__(256, 3) void gemm_qkv128(
    const u16* __restrict__ xhat, const u16* __restrict__ WTcat,
    const float* __restrict__ bfold,
    float* __restrict__ kout, float* __restrict__ vout,
    u16* __restrict__ qbf, u16* __restrict__ kbf, u16* __restrict__ vTb)
{
  __shared__ u16 lds[4 * 128 * GBK];                // [buf][A/B], 32 KiB
  const int t = threadIdx.x;
  // bijective XCD swizzle over 768 blocks (768 % 8 == 0)
  const int sw = (blockIdx.x & 7) * 96 + (blockIdx.x >> 3);
  const int by = sw / 24, bx = sw % 24;
  const int m0 = by * 128, n0 = bx * 128;

  f32x4 acc[4][4] = {};
  core128(xhat, WTcat, m0, n0, t, lds, acc);

  const int lane = t & 63, wave = t >> 6;
  const int wm = wave >> 1, wn = wave & 1;
  const int fr = lane & 15, hi = lane >> 4;
  const int z = n0 >> 10;
  const float* bias = bfold + z * E_DIM;
  const int rowb = hi * 4;
  #pragma unroll
  for (int i = 0; i < 4; ++i) {
    const int mbase = m0 + wm * 64 + i * 16 + rowb;
    #pragma unroll
    for (int j = 0; j < 4; ++j) {
      const int ng = n0 + wn * 64 + j * 16 + fr;
      const int ncol = ng & 1023;
      const float bval = bias[ncol];
      #pragma unroll
      for (int r = 0; r < 4; ++r) {
        const int m = mbase + r;
        const float val = acc[i][j][r] + bval;
        const int b = m >> 11, l = m & 2047, h = ncol >> 6, d = ncol & 63;
        const size_t bh = (size_t)(b * NH + h);
        if (z == 0) {
          qbf[((bh * L_SEQ + l) << 6) + d] = f2bf(val);
        } else if (z == 1) {
          kout[(bh * 64 + d) * L_SEQ + l] = val;
          kbf[((bh * L_SEQ + l) << 6) + d] = f2bf(val);
        } else {
          vout[(bh * L_SEQ + l) * 64 + d] = val;
          vTb[(bh * 64 + d) * L_SEQ + l] = f2bf(val);
        }
      }
    }
  }
}

// ---------------- final GEMM: out = what @ (g_o . Wo) + bfold_o + tokens; 256 blocks ----------------
__global__ __launch_bounds__(256, 3) void gemm_o128(
    const u16* __restrict__ A, const u16* __restrict__ BT, const float* __restrict__ bias,
    const float* __restrict__ tokens, float* __restrict__ out)
{
  __shared__ u16 lds[4 * 128 * GBK];
  const int t = threadIdx.x;
  // bijective XCD swizzle over 256 blocks
  const int sw = (blockIdx.x & 7) * 32 + (blockIdx.x >> 3);
  const int by = sw / 8, bx = sw % 8;
  const int m0 = by * 128, n0 = bx * 128;

  f32x4 acc[4][4] = {};
  core128(A, BT, m0, n0, t, lds, acc);

  const int lane = t & 63, wave = t >> 6;
  const int wm = wave >> 1, wn = wave & 1;
  const int fr = lane & 15, hi = lane >> 4;
  const int rowb = hi * 4;
  #pragma unroll
  for (int i = 0; i < 4; ++i) {
    const int mbase = m0 + wm * 64 + i * 16 + rowb;
    #pragma unroll
    for (int j = 0; j < 4; ++j) {
      const int ncol = n0 + wn * 64 + j * 16 + fr;
      const float bval = bias[ncol];
      #pragma unroll
      for (int r = 0; r < 4; ++r) {
        const int m = mbase + r;
        out[(size_t)m * E_DIM + ncol] = acc[i][j][r] + bval + tokens[(size_t)m * E_DIM + ncol];
      }
    }
  }
}

// ---------------- MFMA flash attention ----------------
// Grid 1024 = one (bh, q-tile) per block, longest q-tile first (qt = 31 - bi>>5).
// K/V LDS double-buffered; issue-early (loads for t+1 before compute t) /
// write-late (regs->LDS[buf^1] after compute) => ONE barrier per KV tile.
// Defer-max (THR=8): skip o-rescale while per-tile max growth <= 8.
__global__ __launch_bounds__(256) void attn_mfma(
    const u16* __restrict__ qbf, const u16* __restrict__ kbf,
    const u16* __restrict__ vTb, u16* __restrict__ wv)
{
  __shared__ u16 Klds[2][64][72];
  __shared__ u16 Vlds[2][64][72];
  __shared__ u16 Plds[4][16][72];
  const int t = threadIdx.x, lane = t & 63, wave = t >> 6;
  const int bi = blockIdx.x;
  const int bh = (bi & 7) + 8 * ((bi >> 3) & 3);   // b*NH + h, XCD-grouped (fixed per bh)
  const int qt = 31 - (bi >> 5);                   // longest-first launch order
  const int fr = lane & 15, hi = lane >> 4;
  const u16* kbase = kbf + (size_t)bh * L_SEQ * 64;
  const u16* vbase = vTb + (size_t)bh * 64 * L_SEQ;
  const int b = bh >> 4, h = bh & 15;

  const int q0w = qt * 64 + wave * 16;
  const int qg = q0w + fr;
  const u16* qrow = qbf + ((size_t)bh * L_SEQ + q0w + fr) * 64 + hi * 8;
  const bf16x8 qf0 = *reinterpret_cast<const bf16x8*>(qrow);
  const bf16x8 qf1 = *reinterpret_cast<const bf16x8*>(qrow + 32);

  f32x4 o[4] = {};                                 // o[dt][r]: q=hi*4+r, d=dt*16+fr
  float mrun = -3.0e38f, lrun = 0.f;

  // per-thread staging: seg = t + s*256; r=seg>>3, c8=(seg&7)*8 (64x64 tile)
  uint4 kreg[2], vreg[2];
  auto LD = [&](int j0) {
    #pragma unroll
    for (int s = 0; s < 2; ++s) {
      const int seg = t + s * 256, r = seg >> 3, c8 = (seg & 7) * 8;
      kreg[s] = *reinterpret_cast<const uint4*>(kbase + (size_t)(j0 + r) * 64 + c8);
      vreg[s] = *reinterpret_cast<const uint4*>(vbase + (size_t)r * L_SEQ + j0 + c8);
    }
  };
  auto ST = [&](int buf) {
    #pragma unroll
    for (int s = 0; s < 2; ++s) {
      const int seg = t + s * 256, r = seg >> 3, c8 = (seg & 7) * 8;
      *reinterpret_cast<uint4*>(&Klds[buf][r][c8]) = kreg[s];
      *reinterpret_cast<uint4*>(&Vlds[buf][r][c8]) = vreg[s];
    }
  };

  LD(0); ST(0);
  __syncthreads();
  #pragma unroll 1
  for (int tkv = 0; tkv <= qt; ++tkv) {
    const int buf = tkv & 1;
    const int j0 = tkv * 64;
    const bool diag = (tkv == qt);
    if (tkv < qt) LD(j0 + 64);                     // issue early: hides under compute

    // S^T = K . Q^T
    f32x4 st[4] = {};
    __builtin_amdgcn_s_setprio(1);
    #pragma unroll
    for (int kt = 0; kt < 4; ++kt) {
      bf16x8 ka0 = *reinterpret_cast<const bf16x8*>(&Klds[buf][kt*16 + fr][hi*8]);
      bf16x8 ka1 = *reinterpret_cast<const bf16x8*>(&Klds[buf][kt*16 + fr][32 + hi*8]);
      st[kt] = __builtin_amdgcn_mfma_f32_16x16x32_bf16(ka0, qf0, st[kt], 0, 0, 0);
      st[kt] = __builtin_amdgcn_mfma_f32_16x16x32_bf16(ka1, qf1, st[kt], 0, 0, 0);
    }
    __builtin_amdgcn_s_setprio(0);

    // mask (diag only) + scale + online softmax with defer-max (THR=8)
    float p[16];
    float pmax = -3.0e38f;
    #pragma unroll
    for (int kt = 0; kt < 4; ++kt)
      #pragma unroll
      for (int r = 0; r < 4; ++r) {
        const int key = j0 + kt*16 + hi*4 + r;
        const float v = st[kt][r] * 0.125f +
                        ((diag && key > qg) ? -1249.875f : 0.f);
        p[kt*4 + r] = v;
        pmax = fmaxf(pmax, v);
      }
    pmax = fmaxf(pmax, __shfl_xor(pmax, 16));
    pmax = fmaxf(pmax, __shfl_xor(pmax, 32));
    if (!__all(pmax - mrun <= 8.f)) {              // rescale only on real max growth
      const float mnew = fmaxf(mrun, pmax);
      const float alpha = __expf(mrun - mnew);
      #pragma unroll
      for (int r = 0; r < 4; ++r) {
        const float ar = __shfl(alpha, hi*4 + r);
        o[0][r] *= ar; o[1][r] *= ar; o[2][r] *= ar; o[3][r] *= ar;
      }
      lrun *= alpha;
      mrun = mnew;
    }
    float lsum = 0.f;
    #pragma unroll
    for (int i = 0; i < 16; ++i) { p[i] = __expf(p[i] - mrun); lsum += p[i]; }
    lsum += __shfl_xor(lsum, 16);
    lsum += __shfl_xor(lsum, 32);
    lrun += lsum;

    // P -> per-wave LDS (bf16), layout P[q=fr][key 0..63]
    #pragma unroll
    for (int kt = 0; kt < 4; ++kt) {
      ushort4 w4;
      w4.x = f2bf(p[kt*4+0]); w4.y = f2bf(p[kt*4+1]);
      w4.z = f2bf(p[kt*4+2]); w4.w = f2bf(p[kt*4+3]);
      *reinterpret_cast<ushort4*>(&Plds[wave][fr][kt*16 + hi*4]) = w4;
    }

    // PV: o += P(16x64) . V(64x64)
    const bf16x8 pf0 = *reinterpret_cast<const bf16x8*>(&Plds[wave][fr][hi*8]);
    const bf16x8 pf1 = *reinterpret_cast<const bf16x8*>(&Plds[wave][fr][32 + hi*8]);
    __builtin_amdgcn_s_setprio(1);
    #pragma unroll
    for (int dt = 0; dt < 4; ++dt) {
      bf16x8 vf0 = *reinterpret_cast<const bf16x8*>(&Vlds[buf][dt*16 + fr][hi*8]);
      bf16x8 vf1 = *reinterpret_cast<const bf16x8*>(&Vlds[buf][dt*16 + fr][32 + hi*8]);
      o[dt] = __builtin_amdgcn_mfma_f32_16x16x32_bf16(pf0, vf0, o[dt], 0, 0, 0);
      o[dt] = __builtin_amdgcn_mfma_f32_16x16x32_bf16(pf1, vf1, o[dt], 0, 0, 0);
    }
    __builtin_amdgcn_s_setprio(0);

    if (tkv < qt) ST(buf ^ 1);                     // write late: buf^1 free since last barrier
    __syncthreads();
  }

  const float inv = 1.f / lrun;
  #pragma unroll
  for (int r = 0; r < 4; ++r) {
    const float ir = __shfl(inv, hi*4 + r);
    const int q = q0w + hi*4 + r;
    u16* dst = wv + (size_t)(b * L_SEQ + q) * E_DIM + h * 64 + fr;
    #pragma unroll
    for (int dt = 0; dt < 4; ++dt)
      dst[dt * 16] = f2bf(o[dt][r] * ir);
  }
}

extern "C" void kernel_launch(void* const* d_in, const int* in_sizes, int n_in,
                              void* d_out, int out_size, void* d_ws, size_t ws_size,
                              hipStream_t stream) {
  (void)in_sizes; (void)n_in; (void)out_size; (void)ws_size;
  const float* tokens = (const float*)d_in[0];
  const float* ln_q_g = (const float*)d_in[1];
  const float* ln_q_b = (const float*)d_in[2];
  const float* Wq     = (const float*)d_in[3];
  const float* bq     = (const float*)d_in[4];
  const float* ln_k_g = (const float*)d_in[5];
  const float* ln_k_b = (const float*)d_in[6];
  const float* Wk     = (const float*)d_in[7];
  const float* bk     = (const float*)d_in[8];
  const float* ln_v_g = (const float*)d_in[9];
  const float* ln_v_b = (const float*)d_in[10];
  const float* Wv     = (const float*)d_in[11];
  const float* bv     = (const float*)d_in[12];
  const float* ln_o_g = (const float*)d_in[13];
  const float* ln_o_b = (const float*)d_in[14];
  const float* Wo     = (const float*)d_in[15];
  const float* bo     = (const float*)d_in[16];

  float* out  = (float*)d_out;            // (2,2048,1024)
  float* kout = out + 4194304;            // (2,16,64,2048)
  float* vout = kout + 4194304;           // (2,16,2048,64)

  char* w = (char*)d_ws;
  const size_t MB = (size_t)1 << 20;
  u16*   WTq   = (u16*)(w + 0 * MB);     // (g_q . Wq)^T — WTq/WTv/WTk contiguous = WTcat (3072 x 1024)
  u16*   WTv   = (u16*)(w + 2 * MB);
  u16*   WTk   = (u16*)(w + 4 * MB);
  u16*   WTo   = (u16*)(w + 6 * MB);     // (g_o . Wo)^T
  u16*   xhat  = (u16*)(w + 8 * MB);     // shared LN x-hat; REUSED as wvb after gemm_qkv
  u16*   qbf   = (u16*)(w + 16 * MB);    // q bf16 (N,H,L,64)
  u16*   kbf   = (u16*)(w + 24 * MB);    // k bf16 (N,H,L,64)
  u16*   vTb   = (u16*)(w + 32 * MB);    // v^T bf16 (N,H,64,L)
  u16*   what  = (u16*)(w + 40 * MB);    // LN x-hat of wv
  float* bfold = (float*)(w + 48 * MB);  // 4 x 1024 folded biases (q, k(Wv), v(Wk), o)
  u16*   wvb   = xhat;                   // attn out (N,L,E) — xhat dead after gemm_qkv

  transpose_all<<<dim3(32, 32, 4), 256, 0, stream>>>(
      Wq, Wv, Wk, Wo, ln_q_g, ln_v_g, ln_k_g, ln_o_g, WTq, WTv, WTk, WTo);
  bias_fold<<<dim3(32, 4), 256, 0, stream>>>(
      Wq, Wv, Wk, Wo, ln_q_b, ln_v_b, ln_k_b, ln_o_b, bq, bv, bk, bo, bfold);
  ln_hat_f32<<<M_ROWS, 256, 0, stream>>>(tokens, xhat);
  gemm_qkv128<<<768, 256, 0, stream>>>(xhat, WTq, bfold, kout, vout, qbf, kbf, vTb);
  attn_mfma<<<1024, 256, 0, stream>>>(qbf, kbf, vTb, wvb);
  ln_hat_bf16<<<M_ROWS, 256, 0, stream>>>(wvb, what);
  gemm_o128<<<256, 256, 0, stream>>>(what, WTo, bfold + 3 * E_DIM, tokens, out);
}

// Round 11
// 142.431 us; speedup vs baseline: 1.2371x; 1.2371x over previous
//
#include <hip/hip_runtime.h>
#include <hip/hip_bf16.h>

#define L_SEQ 2048
#define NH    16
#define E_DIM 1024
#define M_ROWS 4096

typedef unsigned short u16;
typedef unsigned int   u32;
typedef __attribute__((ext_vector_type(8))) __bf16 bf16x8;
typedef __attribute__((ext_vector_type(4))) float  f32x4;

__device__ __forceinline__ u16 f2bf(float f) {
  union { float f; u32 u; } x; x.f = f;
  u32 u = x.u;
  return (u16)((u + 0x7FFFu + ((u >> 16) & 1u)) >> 16);
}
__device__ __forceinline__ float bf2f(u16 v) {
  union { u32 u; float f; } x; x.u = ((u32)v) << 16;
  return x.f;
}
__device__ __forceinline__ void st_bf4(u16* p, float a, float b, float c, float d) {
  ushort4 u; u.x = f2bf(a); u.y = f2bf(b); u.z = f2bf(c); u.w = f2bf(d);
  *reinterpret_cast<ushort4*>(p) = u;
}
// hardware packed f32x2 -> bf16x2 (v_cvt_pk_bf16_f32, RTNE) — 1 op vs ~8 for software f2bf x2
__device__ __forceinline__ u32 pkbf(float a, float b) {
  __hip_bfloat162 h = __float22bfloat162_rn(float2{a, b});
  return *reinterpret_cast<u32*>(&h);
}
// async global->LDS, 16B per lane; LDS dest must be linear in lane order
__device__ __forceinline__ void gload16(const u16* g, u16* l) {
  __builtin_amdgcn_global_load_lds(
      (const __attribute__((address_space(1))) void*)g,
      (__attribute__((address_space(3))) void*)l, 16, 0, 0);
}
#define SBAR() asm volatile("s_barrier" ::: "memory")

// ---------------- LayerNorm x-hat only (g/b folded into weights/bias): fp32 in -> bf16 out ----------------
__global__ __launch_bounds__(256) void ln_hat_f32(const float* __restrict__ x, u16* __restrict__ o)
{
  __shared__ float red[8];
  const size_t row = blockIdx.x;
  const int t = threadIdx.x;
  float4 v = reinterpret_cast<const float4*>(x + row * E_DIM)[t];
  float s = v.x + v.y + v.z + v.w;
  float q = v.x*v.x + v.y*v.y + v.z*v.z + v.w*v.w;
  #pragma unroll
  for (int off = 32; off; off >>= 1) { s += __shfl_down(s, off); q += __shfl_down(q, off); }
  if ((t & 63) == 0) { red[t >> 6] = s; red[4 + (t >> 6)] = q; }
  __syncthreads();
  float S = red[0] + red[1] + red[2] + red[3];
  float Q = red[4] + red[5] + red[6] + red[7];
  float mean = S * (1.f / E_DIM);
  float rstd = rsqrtf(Q * (1.f / E_DIM) - mean * mean + 1e-5f);
  st_bf4(o + row * E_DIM + t * 4,
         (v.x - mean) * rstd, (v.y - mean) * rstd, (v.z - mean) * rstd, (v.w - mean) * rstd);
}

// ---------------- LayerNorm x-hat only: bf16 in -> bf16 out ----------------
__global__ __launch_bounds__(256) void ln_hat_bf16(const u16* __restrict__ x, u16* __restrict__ o)
{
  __shared__ float red[8];
  const size_t row = blockIdx.x;
  const int t = threadIdx.x;
  ushort4 u = reinterpret_cast<const ushort4*>(x + row * E_DIM)[t];
  float v0 = bf2f(u.x), v1 = bf2f(u.y), v2 = bf2f(u.z), v3 = bf2f(u.w);
  float s = v0 + v1 + v2 + v3;
  float q = v0*v0 + v1*v1 + v2*v2 + v3*v3;
  #pragma unroll
  for (int off = 32; off; off >>= 1) { s += __shfl_down(s, off); q += __shfl_down(q, off); }
  if ((t & 63) == 0) { red[t >> 6] = s; red[4 + (t >> 6)] = q; }
  __syncthreads();
  float S = red[0] + red[1] + red[2] + red[3];
  float Q = red[4] + red[5] + red[6] + red[7];
  float mean = S * (1.f / E_DIM);
  float rstd = rsqrtf(Q * (1.f / E_DIM) - mean * mean + 1e-5f);
  st_bf4(o + row * E_DIM + t * 4,
         (v0 - mean) * rstd, (v1 - mean) * rstd, (v2 - mean) * rstd, (v3 - mean) * rstd);
}

// ---------------- fused weight transposes + LN-gamma fold: WT[n,e] = bf16(W[e,n] * g[e]) ----------------
__global__ __launch_bounds__(256) void transpose_all(
    const float* __restrict__ W0, const float* __restrict__ W1,
    const float* __restrict__ W2, const float* __restrict__ W3,
    const float* __restrict__ g0, const float* __restrict__ g1,
    const float* __restrict__ g2, const float* __restrict__ g3,
    u16* __restrict__ T0, u16* __restrict__ T1, u16* __restrict__ T2, u16* __restrict__ T3)
{
  __shared__ float tile[32][33];
  const int z = blockIdx.z;
  const float* W = (z == 0) ? W0 : (z == 1) ? W1 : (z == 2) ? W2 : W3;
  const float* g = (z == 0) ? g0 : (z == 1) ? g1 : (z == 2) ? g2 : g3;
  u16* T = (z == 0) ? T0 : (z == 1) ? T1 : (z == 2) ? T2 : T3;
  const int tx = threadIdx.x & 31, ty = threadIdx.x >> 5;
  const int bx = blockIdx.x * 32, by = blockIdx.y * 32;
  #pragma unroll
  for (int r = 0; r < 4; ++r) {
    const int e = by + ty + r * 8;
    tile[ty + r * 8][tx] = W[(size_t)e * E_DIM + bx + tx] * g[e];
  }
  __syncthreads();
  #pragma unroll
  for (int r = 0; r < 4; ++r)
    T[(size_t)(bx + ty + r * 8) * E_DIM + by + tx] = f2bf(tile[tx][ty + r * 8]);
}

// ---------------- bias fold (parallel): bfold[z][n] = bias_z[n] + sum_e bln_z[e] * W_z[e,n] ----------------
__global__ __launch_bounds__(256) void bias_fold(
    const float* __restrict__ W0, const float* __restrict__ W1,
    const float* __restrict__ W2, const float* __restrict__ W3,
    const float* __restrict__ l0, const float* __restrict__ l1,
    const float* __restrict__ l2, const float* __restrict__ l3,
    const float* __restrict__ b0, const float* __restrict__ b1,
    const float* __restrict__ b2, const float* __restrict__ b3,
    float* __restrict__ bfold)
{
  __shared__ float part[8][32];
  const int z = blockIdx.y;
  const float* W  = (z == 0) ? W0 : (z == 1) ? W1 : (z == 2) ? W2 : W3;
  const float* bl = (z == 0) ? l0 : (z == 1) ? l1 : (z == 2) ? l2 : l3;
  const float* bs = (z == 0) ? b0 : (z == 1) ? b1 : (z == 2) ? b2 : b3;
  const int tn = threadIdx.x & 31, te = threadIdx.x >> 5;
  const int n = blockIdx.x * 32 + tn;
  float acc = 0.f;
  const int e0 = te * 128;
  for (int e = e0; e < e0 + 128; ++e) acc += bl[e] * W[(size_t)e * E_DIM + n];
  part[te][tn] = acc;
  __syncthreads();
  if (te == 0) {
    float s = part[0][tn] + part[1][tn] + part[2][tn] + part[3][tn]
            + part[4][tn] + part[5][tn] + part[6][tn] + part[7][tn];
    bfold[z * E_DIM + n] = bs[n] + s;
  }
}

// ---------------- 128x128 counted-vmcnt GEMM core, BK=64, 4 waves, 64 KB LDS (R8-proven) ----------------
// Discipline: [bar: done reading buf^1] -> STAGE(kt+1 into buf^1) -> vmcnt(8):
// own kt loads done -> [bar: ALL waves' kt loads landed] -> PHASES(kt).
// LDS chunk-XOR swizzle both-sides (pre-swizzled global source + swizzled read).
#define GBK 64
__device__ __forceinline__ void core128(
    const u16* __restrict__ A, const u16* __restrict__ BT,
    int m0, int n0, int t, u16* lds, f32x4 (&acc)[4][4])
{
  const int lane = t & 63, wave = t >> 6;
  const int wm = wave >> 1, wn = wave & 1;
  const int fr = lane & 15, hi = lane >> 4;
  const int sx = fr & 7;

  auto STAGE = [&](int buf, int kt) {
    u16* la = lds + (buf * 2 + 0) * (128 * GBK);
    u16* lb = lds + (buf * 2 + 1) * (128 * GBK);
    #pragma unroll
    for (int s = 0; s < 4; ++s) {
      const int seg = t + s * 256;
      const int r = seg >> 3;
      const int gc = (seg & 7) ^ (r & 7);            // inverse-swizzled source chunk
      gload16(A + (size_t)(m0 + r) * E_DIM + kt * GBK + gc * 8, la + seg * 8);
    }
    #pragma unroll
    for (int s = 0; s < 4; ++s) {
      const int seg = t + s * 256;
      const int r = seg >> 3;
      const int gc = (seg & 7) ^ (r & 7);
      gload16(BT + (size_t)(n0 + r) * E_DIM + kt * GBK + gc * 8, lb + seg * 8);
    }
  };
  auto AF = [&](int buf, int i, int ks) -> bf16x8 {
    return *reinterpret_cast<const bf16x8*>(
        lds + (buf * 2 + 0) * (128 * GBK) + (wm * 64 + i * 16 + fr) * GBK + (((ks * 4 + hi) ^ sx) * 8));
  };
  auto BF = [&](int buf, int j, int ks) -> bf16x8 {
    return *reinterpret_cast<const bf16x8*>(
        lds + (buf * 2 + 1) * (128 * GBK) + (wn * 64 + j * 16 + fr) * GBK + (((ks * 4 + hi) ^ sx) * 8));
  };
  auto PHASES = [&](int buf) {
    bf16x8 a[4][2], b[4][2];
    #pragma unroll
    for (int i = 0; i < 4; ++i) { a[i][0] = AF(buf, i, 0); a[i][1] = AF(buf, i, 1); }
    #pragma unroll
    for (int j = 0; j < 4; ++j) { b[j][0] = BF(buf, j, 0); b[j][1] = BF(buf, j, 1); }
    __builtin_amdgcn_s_setprio(1);
    #pragma unroll
    for (int i = 0; i < 4; ++i)
      #pragma unroll
      for (int j = 0; j < 4; ++j) {
        acc[i][j] = __builtin_amdgcn_mfma_f32_16x16x32_bf16(a[i][0], b[j][0], acc[i][j], 0, 0, 0);
        acc[i][j] = __builtin_amdgcn_mfma_f32_16x16x32_bf16(a[i][1], b[j][1], acc[i][j], 0, 0, 0);
      }
    __builtin_amdgcn_s_setprio(0);
  };

  STAGE(0, 0);                                      // prologue: kt0's 8 loads in flight
  #pragma unroll 1
  for (int kt = 0; kt < 15; ++kt) {
    const int buf = kt & 1;
    SBAR();                                         // all waves done reading buf^1 (kt-1)
    STAGE(buf ^ 1, kt + 1);                         // kt+1's 8 loads: stay in flight
    asm volatile("s_waitcnt vmcnt(8)" ::: "memory");// own kt loads done
    SBAR();                                         // => ALL waves' kt loads landed
    PHASES(buf);
  }
  asm volatile("s_waitcnt vmcnt(0)" ::: "memory");  // peeled last K-tile (kt=15, buf=1)
  SBAR();
  PHASES(1);
}

// ---------------- fused QKV GEMM: 768 blocks (32m x 24n), z = n0>>10 ----------------
// XCD-rectangle mapping: each XCD owns an 8m x 12n rectangle (5 MB working set, was 7).
__global__ __launch_bounds__(256, 2) void gemm_qkv128(
    const u16* __restrict__ xhat, const u16* __restrict__ WTcat,
    const float* __restrict__ bfold,
    float* __restrict__ kout, float* __restrict__ vout,
    u16* __restrict__ qbf, u16* __restrict__ kbf, u16* __restrict__ vTb)
{
  __shared__ u16 lds[4 * 128 * GBK];                // [buf][A/B], 64 KiB
  const int t = threadIdx.x;
  const int xcd = blockIdx.x & 7, l = blockIdx.x >> 3;  // l in [0,96)
  const int by = 8 * (xcd >> 1) + l / 12;
  const int bx = 12 * (xcd & 1) + l % 12;
  const int m0 = by * 128, n0 = bx * 128;

  f32x4 acc[4][4] = {};
  core128(xhat, WTcat, m0, n0, t, lds, acc);

  const int lane = t & 63, wave = t >> 6;
  const int wm = wave >> 1, wn = wave & 1;
  const int fr = lane & 15, hi = lane >> 4;
  const int z = n0 >> 10;
  const float* bias = bfold + z * E_DIM;
  const int rowb = hi * 4;
  #pragma unroll
  for (int i = 0; i < 4; ++i) {
    const int mbase = m0 + wm * 64 + i * 16 + rowb;
    #pragma unroll
    for (int j = 0; j < 4; ++j) {
      const int ng = n0 + wn * 64 + j * 16 + fr;
      const int ncol = ng & 1023;
      const float bval = bias[ncol];
      #pragma unroll
      for (int r = 0; r < 4; ++r) {
        const int m = mbase + r;
        const float val = acc[i][j][r] + bval;
        const int b = m >> 11, ltok = m & 2047, h = ncol >> 6, d = ncol & 63;
        const size_t bh = (size_t)(b * NH + h);
        if (z == 0) {
          qbf[((bh * L_SEQ + ltok) << 6) + d] = f2bf(val);
        } else if (z == 1) {
          kout[(bh * 64 + d) * L_SEQ + ltok] = val;
          kbf[((bh * L_SEQ + ltok) << 6) + d] = f2bf(val);
        } else {
          vout[(bh * L_SEQ + ltok) * 64 + d] = val;
          vTb[(bh * 64 + d) * L_SEQ + ltok] = f2bf(val);
        }
      }
    }
  }
}

// ---------------- final GEMM: out = what @ (g_o . Wo) + bfold_o + tokens; 256 blocks ----------------
// XCD-rectangle mapping: 8m x 4n rectangle per XCD (3 MB working set — L2-fits).
__global__ __launch_bounds__(256, 2) void gemm_o128(
    const u16* __restrict__ A, const u16* __restrict__ BT, const float* __restrict__ bias,
    const float* __restrict__ tokens, float* __restrict__ out)
{
  __shared__ u16 lds[4 * 128 * GBK];
  const int t = threadIdx.x;
  const int xcd = blockIdx.x & 7, l = blockIdx.x >> 3;  // l in [0,32)
  const int by = 8 * (xcd >> 1) + (l >> 2);
  const int bx = 4 * (xcd & 1) + (l & 3);
  const int m0 = by * 128, n0 = bx * 128;

  f32x4 acc[4][4] = {};
  core128(A, BT, m0, n0, t, lds, acc);

  const int lane = t & 63, wave = t >> 6;
  const int wm = wave >> 1, wn = wave & 1;
  const int fr = lane & 15, hi = lane >> 4;
  const int rowb = hi * 4;
  #pragma unroll
  for (int i = 0; i < 4; ++i) {
    const int mbase = m0 + wm * 64 + i * 16 + rowb;
    #pragma unroll
    for (int j = 0; j < 4; ++j) {
      const int ncol = n0 + wn * 64 + j * 16 + fr;
      const float bval = bias[ncol];
      #pragma unroll
      for (int r = 0; r < 4; ++r) {
        const int m = mbase + r;
        out[(size_t)m * E_DIM + ncol] = acc[i][j][r] + bval + tokens[(size_t)m * E_DIM + ncol];
      }
    }
  }
}

// ---------------- MFMA flash attention, q-tile-paired (R8 structure) ----------------
// VALU diet vs R8: (1) softmax in log2 domain — score fma folds 0.125*log2e, exp2f = bare
// v_exp_f32 (saves 16 muls/tile); (2) P pack via v_cvt_pk_bf16_f32 (8 ops vs ~64 software).
__global__ __launch_bounds__(256) void attn_mfma(
    const u16* __restrict__ qbf, const u16* __restrict__ kbf,
    const u16* __restrict__ vTb, u16* __restrict__ wv)
{
  __shared__ u16 Klds[64][72];
  __shared__ u16 Vlds[64][72];
  __shared__ u16 Plds[4][16][72];
  const int t = threadIdx.x, lane = t & 63, wave = t >> 6;
  const int bi = blockIdx.x;
  const int bh = (bi & 7) + 8 * ((bi >> 3) & 3);   // b*NH + h, XCD-grouped
  const int pr = bi >> 5;                          // pair index 0..15
  const int fr = lane & 15, hi = lane >> 4;
  const u16* kbase = kbf + (size_t)bh * L_SEQ * 64;
  const u16* vbase = vTb + (size_t)bh * 64 * L_SEQ;
  const int b = bh >> 4, h = bh & 15;
  const float kSC2  = 0.125f * 1.44269504089f;     // score scale in log2 domain
  const float kMSK2 = -1803.2f;                    // -1249.875 * log2e

  #pragma unroll 1
  for (int half = 0; half < 2; ++half) {
    const int qt = half ? (31 - pr) : pr;
    const int q0w = qt * 64 + wave * 16;
    const int qg = q0w + fr;

    const u16* qrow = qbf + ((size_t)bh * L_SEQ + q0w + fr) * 64 + hi * 8;
    const bf16x8 qf0 = *reinterpret_cast<const bf16x8*>(qrow);
    const bf16x8 qf1 = *reinterpret_cast<const bf16x8*>(qrow + 32);

    f32x4 o[4] = {};
    float mrun = -3.0e38f, lrun = 0.f;             // mrun in log2 domain

    for (int tkv = 0; tkv <= qt; ++tkv) {
      const int j0 = tkv * 64;
      const bool diag = (tkv == qt);
      #pragma unroll
      for (int s = 0; s < 2; ++s) {
        const int seg = t + s * 256;
        const int r = seg >> 3, c8 = (seg & 7) * 8;
        *reinterpret_cast<uint4*>(&Klds[r][c8]) =
            *reinterpret_cast<const uint4*>(kbase + (size_t)(j0 + r) * 64 + c8);
        *reinterpret_cast<uint4*>(&Vlds[r][c8]) =
            *reinterpret_cast<const uint4*>(vbase + (size_t)r * L_SEQ + j0 + c8);
      }
      __syncthreads();

      f32x4 st[4] = {};
      __builtin_amdgcn_s_setprio(1);
      #pragma unroll
      for (int kt = 0; kt < 4; ++kt) {
        bf16x8 ka0 = *reinterpret_cast<const bf16x8*>(&Klds[kt*16 + fr][hi*8]);
        bf16x8 ka1 = *reinterpret_cast<const bf16x8*>(&Klds[kt*16 + fr][32 + hi*8]);
        st[kt] = __builtin_amdgcn_mfma_f32_16x16x32_bf16(ka0, qf0, st[kt], 0, 0, 0);
        st[kt] = __builtin_amdgcn_mfma_f32_16x16x32_bf16(ka1, qf1, st[kt], 0, 0, 0);
      }
      __builtin_amdgcn_s_setprio(0);

      float p[16];
      float pmax = -3.0e38f;
      #pragma unroll
      for (int kt = 0; kt < 4; ++kt)
        #pragma unroll
        for (int r = 0; r < 4; ++r) {
          const int key = j0 + kt*16 + hi*4 + r;
          const float v = st[kt][r] * kSC2 + ((diag && key > qg) ? kMSK2 : 0.f);
          p[kt*4 + r] = v;
          pmax = fmaxf(pmax, v);
        }
      pmax = fmaxf(pmax, __shfl_xor(pmax, 16));
      pmax = fmaxf(pmax, __shfl_xor(pmax, 32));
      const float mnew = fmaxf(mrun, pmax);
      const float alpha = exp2f(mrun - mnew);
      float lsum = 0.f;
      #pragma unroll
      for (int i = 0; i < 16; ++i) { p[i] = exp2f(p[i] - mnew); lsum += p[i]; }
      lsum += __shfl_xor(lsum, 16);
      lsum += __shfl_xor(lsum, 32);
      lrun = lrun * alpha + lsum;
      mrun = mnew;
      #pragma unroll
      for (int r = 0; r < 4; ++r) {
        const float ar = __shfl(alpha, hi*4 + r);
        o[0][r] *= ar; o[1][r] *= ar; o[2][r] *= ar; o[3][r] *= ar;
      }

      // P -> per-wave LDS via hardware cvt_pk (keys hi*4+0..3 per chunk)
      #pragma unroll
      for (int kt = 0; kt < 4; ++kt) {
        uint2 w2;
        w2.x = pkbf(p[kt*4+0], p[kt*4+1]);
        w2.y = pkbf(p[kt*4+2], p[kt*4+3]);
        *reinterpret_cast<uint2*>(&Plds[wave][fr][kt*16 + hi*4]) = w2;
      }

      const bf16x8 pf0 = *reinterpret_cast<const bf16x8*>(&Plds[wave][fr][hi*8]);
      const bf16x8 pf1 = *reinterpret_cast<const bf16x8*>(&Plds[wave][fr][32 + hi*8]);
      __builtin_amdgcn_s_setprio(1);
      #pragma unroll
      for (int dt = 0; dt < 4; ++dt) {
        bf16x8 vf0 = *reinterpret_cast<const bf16x8*>(&Vlds[dt*16 + fr][hi*8]);
        bf16x8 vf1 = *reinterpret_cast<const bf16x8*>(&Vlds[dt*16 + fr][32 + hi*8]);
        o[dt] = __builtin_amdgcn_mfma_f32_16x16x32_bf16(pf0, vf0, o[dt], 0, 0, 0);
        o[dt] = __builtin_amdgcn_mfma_f32_16x16x32_bf16(pf1, vf1, o[dt], 0, 0, 0);
      }
      __builtin_amdgcn_s_setprio(0);
      __syncthreads();
    }

    const float inv = 1.f / lrun;
    #pragma unroll
    for (int r = 0; r < 4; ++r) {
      const float ir = __shfl(inv, hi*4 + r);
      const int q = q0w + hi*4 + r;
      u16* dst = wv + (size_t)(b * L_SEQ + q) * E_DIM + h * 64 + fr;
      #pragma unroll
      for (int dt = 0; dt < 4; ++dt)
        dst[dt * 16] = f2bf(o[dt][r] * ir);
    }
  }
}

extern "C" void kernel_launch(void* const* d_in, const int* in_sizes, int n_in,
                              void* d_out, int out_size, void* d_ws, size_t ws_size,
                              hipStream_t stream) {
  (void)in_sizes; (void)n_in; (void)out_size; (void)ws_size;
  const float* tokens = (const float*)d_in[0];
  const float* ln_q_g = (const float*)d_in[1];
  const float* ln_q_b = (const float*)d_in[2];
  const float* Wq     = (const float*)d_in[3];
  const float* bq     = (const float*)d_in[4];
  const float* ln_k_g = (const float*)d_in[5];
  const float* ln_k_b = (const float*)d_in[6];
  const float* Wk     = (const float*)d_in[7];
  const float* bk     = (const float*)d_in[8];
  const float* ln_v_g = (const float*)d_in[9];
  const float* ln_v_b = (const float*)d_in[10];
  const float* Wv     = (const float*)d_in[11];
  const float* bv     = (const float*)d_in[12];
  const float* ln_o_g = (const float*)d_in[13];
  const float* ln_o_b = (const float*)d_in[14];
  const float* Wo     = (const float*)d_in[15];
  const float* bo     = (const float*)d_in[16];

  float* out  = (float*)d_out;            // (2,2048,1024)
  float* kout = out + 4194304;            // (2,16,64,2048)
  float* vout = kout + 4194304;           // (2,16,2048,64)

  char* w = (char*)d_ws;
  const size_t MB = (size_t)1 << 20;
  u16*   WTq   = (u16*)(w + 0 * MB);     // (g_q . Wq)^T — WTq/WTv/WTk contiguous = WTcat (3072 x 1024)
  u16*   WTv   = (u16*)(w + 2 * MB);
  u16*   WTk   = (u16*)(w + 4 * MB);
  u16*   WTo   = (u16*)(w + 6 * MB);     // (g_o . Wo)^T
  u16*   xhat  = (u16*)(w + 8 * MB);     // shared LN x-hat; REUSED as wvb after gemm_qkv
  u16*   qbf   = (u16*)(w + 16 * MB);    // q bf16 (N,H,L,64)
  u16*   kbf   = (u16*)(w + 24 * MB);    // k bf16 (N,H,L,64)
  u16*   vTb   = (u16*)(w + 32 * MB);    // v^T bf16 (N,H,64,L)
  u16*   what  = (u16*)(w + 40 * MB);    // LN x-hat of wv
  float* bfold = (float*)(w + 48 * MB);  // 4 x 1024 folded biases (q, k(Wv), v(Wk), o)
  u16*   wvb   = xhat;                   // attn out (N,L,E) — xhat dead after gemm_qkv

  transpose_all<<<dim3(32, 32, 4), 256, 0, stream>>>(
      Wq, Wv, Wk, Wo, ln_q_g, ln_v_g, ln_k_g, ln_o_g, WTq, WTv, WTk, WTo);
  bias_fold<<<dim3(32, 4), 256, 0, stream>>>(
      Wq, Wv, Wk, Wo, ln_q_b, ln_v_b, ln_k_b, ln_o_b, bq, bv, bk, bo, bfold);
  ln_hat_f32<<<M_ROWS, 256, 0, stream>>>(tokens, xhat);
  gemm_qkv128<<<768, 256, 0, stream>>>(xhat, WTq, bfold, kout, vout, qbf, kbf, vTb);
  attn_mfma<<<512, 256, 0, stream>>>(qbf, kbf, vTb, wvb);
  ln_hat_bf16<<<M_ROWS, 256, 0, stream>>>(wvb, what);
  gemm_o128<<<256, 256, 0, stream>>>(what, WTo, bfold + 3 * E_DIM, tokens, out);
}

// Round 12
// 139.615 us; speedup vs baseline: 1.2621x; 1.0202x over previous
//
#include <hip/hip_runtime.h>

#define L_SEQ 2048
#define NH    16
#define E_DIM 1024
#define M_ROWS 4096

typedef unsigned short u16;
typedef unsigned int   u32;
typedef __attribute__((ext_vector_type(8))) __bf16 bf16x8;
typedef __attribute__((ext_vector_type(4))) float  f32x4;

__device__ __forceinline__ u16 f2bf(float f) {
  union { float f; u32 u; } x; x.f = f;
  u32 u = x.u;
  return (u16)((u + 0x7FFFu + ((u >> 16) & 1u)) >> 16);
}
__device__ __forceinline__ float bf2f(u16 v) {
  union { u32 u; float f; } x; x.u = ((u32)v) << 16;
  return x.f;
}
__device__ __forceinline__ void st_bf4(u16* p, float a, float b, float c, float d) {
  ushort4 u; u.x = f2bf(a); u.y = f2bf(b); u.z = f2bf(c); u.w = f2bf(d);
  *reinterpret_cast<ushort4*>(p) = u;
}
// truncation pack: two f32 -> u32 of 2 bf16 (3 VALU ops; P >= 0 so error <= 2^-8 downward)
__device__ __forceinline__ u32 pktrunc(float a, float b) {
  union { float f; u32 u; } xa, xb; xa.f = a; xb.f = b;
  return (xa.u >> 16) | (xb.u & 0xFFFF0000u);
}
// async global->LDS, 16B per lane; LDS dest must be linear in lane order
__device__ __forceinline__ void gload16(const u16* g, u16* l) {
  __builtin_amdgcn_global_load_lds(
      (const __attribute__((address_space(1))) void*)g,
      (__attribute__((address_space(3))) void*)l, 16, 0, 0);
}
#define SBAR() asm volatile("s_barrier" ::: "memory")

// ---------------- LayerNorm x-hat only (g/b folded into weights/bias): fp32 in -> bf16 out ----------------
__global__ __launch_bounds__(256) void ln_hat_f32(const float* __restrict__ x, u16* __restrict__ o)
{
  __shared__ float red[8];
  const size_t row = blockIdx.x;
  const int t = threadIdx.x;
  float4 v = reinterpret_cast<const float4*>(x + row * E_DIM)[t];
  float s = v.x + v.y + v.z + v.w;
  float q = v.x*v.x + v.y*v.y + v.z*v.z + v.w*v.w;
  #pragma unroll
  for (int off = 32; off; off >>= 1) { s += __shfl_down(s, off); q += __shfl_down(q, off); }
  if ((t & 63) == 0) { red[t >> 6] = s; red[4 + (t >> 6)] = q; }
  __syncthreads();
  float S = red[0] + red[1] + red[2] + red[3];
  float Q = red[4] + red[5] + red[6] + red[7];
  float mean = S * (1.f / E_DIM);
  float rstd = rsqrtf(Q * (1.f / E_DIM) - mean * mean + 1e-5f);
  st_bf4(o + row * E_DIM + t * 4,
         (v.x - mean) * rstd, (v.y - mean) * rstd, (v.z - mean) * rstd, (v.w - mean) * rstd);
}

// ---------------- LayerNorm x-hat only: bf16 in -> bf16 out ----------------
__global__ __launch_bounds__(256) void ln_hat_bf16(const u16* __restrict__ x, u16* __restrict__ o)
{
  __shared__ float red[8];
  const size_t row = blockIdx.x;
  const int t = threadIdx.x;
  ushort4 u = reinterpret_cast<const ushort4*>(x + row * E_DIM)[t];
  float v0 = bf2f(u.x), v1 = bf2f(u.y), v2 = bf2f(u.z), v3 = bf2f(u.w);
  float s = v0 + v1 + v2 + v3;
  float q = v0*v0 + v1*v1 + v2*v2 + v3*v3;
  #pragma unroll
  for (int off = 32; off; off >>= 1) { s += __shfl_down(s, off); q += __shfl_down(q, off); }
  if ((t & 63) == 0) { red[t >> 6] = s; red[4 + (t >> 6)] = q; }
  __syncthreads();
  float S = red[0] + red[1] + red[2] + red[3];
  float Q = red[4] + red[5] + red[6] + red[7];
  float mean = S * (1.f / E_DIM);
  float rstd = rsqrtf(Q * (1.f / E_DIM) - mean * mean + 1e-5f);
  st_bf4(o + row * E_DIM + t * 4,
         (v0 - mean) * rstd, (v1 - mean) * rstd, (v2 - mean) * rstd, (v3 - mean) * rstd);
}

// ---------------- fused weight transposes + LN-gamma fold: WT[n,e] = bf16(W[e,n] * g[e]) ----------------
__global__ __launch_bounds__(256) void transpose_all(
    const float* __restrict__ W0, const float* __restrict__ W1,
    const float* __restrict__ W2, const float* __restrict__ W3,
    const float* __restrict__ g0, const float* __restrict__ g1,
    const float* __restrict__ g2, const float* __restrict__ g3,
    u16* __restrict__ T0, u16* __restrict__ T1, u16* __restrict__ T2, u16* __restrict__ T3)
{
  __shared__ float tile[32][33];
  const int z = blockIdx.z;
  const float* W = (z == 0) ? W0 : (z == 1) ? W1 : (z == 2) ? W2 : W3;
  const float* g = (z == 0) ? g0 : (z == 1) ? g1 : (z == 2) ? g2 : g3;
  u16* T = (z == 0) ? T0 : (z == 1) ? T1 : (z == 2) ? T2 : T3;
  const int tx = threadIdx.x & 31, ty = threadIdx.x >> 5;
  const int bx = blockIdx.x * 32, by = blockIdx.y * 32;
  #pragma unroll
  for (int r = 0; r < 4; ++r) {
    const int e = by + ty + r * 8;
    tile[ty + r * 8][tx] = W[(size_t)e * E_DIM + bx + tx] * g[e];
  }
  __syncthreads();
  #pragma unroll
  for (int r = 0; r < 4; ++r)
    T[(size_t)(bx + ty + r * 8) * E_DIM + by + tx] = f2bf(tile[tx][ty + r * 8]);
}

// ---------------- bias fold (parallel): bfold[z][n] = bias_z[n] + sum_e bln_z[e] * W_z[e,n] ----------------
__global__ __launch_bounds__(256) void bias_fold(
    const float* __restrict__ W0, const float* __restrict__ W1,
    const float* __restrict__ W2, const float* __restrict__ W3,
    const float* __restrict__ l0, const float* __restrict__ l1,
    const float* __restrict__ l2, const float* __restrict__ l3,
    const float* __restrict__ b0, const float* __restrict__ b1,
    const float* __restrict__ b2, const float* __restrict__ b3,
    float* __restrict__ bfold)
{
  __shared__ float part[8][32];
  const int z = blockIdx.y;
  const float* W  = (z == 0) ? W0 : (z == 1) ? W1 : (z == 2) ? W2 : W3;
  const float* bl = (z == 0) ? l0 : (z == 1) ? l1 : (z == 2) ? l2 : l3;
  const float* bs = (z == 0) ? b0 : (z == 1) ? b1 : (z == 2) ? b2 : b3;
  const int tn = threadIdx.x & 31, te = threadIdx.x >> 5;
  const int n = blockIdx.x * 32 + tn;
  float acc = 0.f;
  const int e0 = te * 128;
  for (int e = e0; e < e0 + 128; ++e) acc += bl[e] * W[(size_t)e * E_DIM + n];
  part[te][tn] = acc;
  __syncthreads();
  if (te == 0) {
    float s = part[0][tn] + part[1][tn] + part[2][tn] + part[3][tn]
            + part[4][tn] + part[5][tn] + part[6][tn] + part[7][tn];
    bfold[z * E_DIM + n] = bs[n] + s;
  }
}

// ---------------- 128x128 counted-vmcnt GEMM core, BK=64, 4 waves, 64 KB LDS (R8-proven) ----------------
// Discipline: [bar: done reading buf^1] -> STAGE(kt+1 into buf^1) -> vmcnt(8):
// own kt loads done -> [bar: ALL waves' kt loads landed] -> PHASES(kt).
// LDS chunk-XOR swizzle both-sides (pre-swizzled global source + swizzled read).
#define GBK 64
__device__ __forceinline__ void core128(
    const u16* __restrict__ A, const u16* __restrict__ BT,
    int m0, int n0, int t, u16* lds, f32x4 (&acc)[4][4])
{
  const int lane = t & 63, wave = t >> 6;
  const int wm = wave >> 1, wn = wave & 1;
  const int fr = lane & 15, hi = lane >> 4;
  const int sx = fr & 7;

  auto STAGE = [&](int buf, int kt) {
    u16* la = lds + (buf * 2 + 0) * (128 * GBK);
    u16* lb = lds + (buf * 2 + 1) * (128 * GBK);
    #pragma unroll
    for (int s = 0; s < 4; ++s) {
      const int seg = t + s * 256;
      const int r = seg >> 3;
      const int gc = (seg & 7) ^ (r & 7);            // inverse-swizzled source chunk
      gload16(A + (size_t)(m0 + r) * E_DIM + kt * GBK + gc * 8, la + seg * 8);
    }
    #pragma unroll
    for (int s = 0; s < 4; ++s) {
      const int seg = t + s * 256;
      const int r = seg >> 3;
      const int gc = (seg & 7) ^ (r & 7);
      gload16(BT + (size_t)(n0 + r) * E_DIM + kt * GBK + gc * 8, lb + seg * 8);
    }
  };
  auto AF = [&](int buf, int i, int ks) -> bf16x8 {
    return *reinterpret_cast<const bf16x8*>(
        lds + (buf * 2 + 0) * (128 * GBK) + (wm * 64 + i * 16 + fr) * GBK + (((ks * 4 + hi) ^ sx) * 8));
  };
  auto BF = [&](int buf, int j, int ks) -> bf16x8 {
    return *reinterpret_cast<const bf16x8*>(
        lds + (buf * 2 + 1) * (128 * GBK) + (wn * 64 + j * 16 + fr) * GBK + (((ks * 4 + hi) ^ sx) * 8));
  };
  auto PHASES = [&](int buf) {
    bf16x8 a[4][2], b[4][2];
    #pragma unroll
    for (int i = 0; i < 4; ++i) { a[i][0] = AF(buf, i, 0); a[i][1] = AF(buf, i, 1); }
    #pragma unroll
    for (int j = 0; j < 4; ++j) { b[j][0] = BF(buf, j, 0); b[j][1] = BF(buf, j, 1); }
    __builtin_amdgcn_s_setprio(1);
    #pragma unroll
    for (int i = 0; i < 4; ++i)
      #pragma unroll
      for (int j = 0; j < 4; ++j) {
        acc[i][j] = __builtin_amdgcn_mfma_f32_16x16x32_bf16(a[i][0], b[j][0], acc[i][j], 0, 0, 0);
        acc[i][j] = __builtin_amdgcn_mfma_f32_16x16x32_bf16(a[i][1], b[j][1], acc[i][j], 0, 0, 0);
      }
    __builtin_amdgcn_s_setprio(0);
  };

  STAGE(0, 0);                                      // prologue: kt0's 8 loads in flight
  #pragma unroll 1
  for (int kt = 0; kt < 15; ++kt) {
    const int buf = kt & 1;
    SBAR();                                         // all waves done reading buf^1 (kt-1)
    STAGE(buf ^ 1, kt + 1);                         // kt+1's 8 loads: stay in flight
    asm volatile("s_waitcnt vmcnt(8)" ::: "memory");// own kt loads done
    SBAR();                                         // => ALL waves' kt loads landed
    PHASES(buf);
  }
  asm volatile("s_waitcnt vmcnt(0)" ::: "memory");  // peeled last K-tile (kt=15, buf=1)
  SBAR();
  PHASES(1);
}

// ---------------- fused QKV GEMM: 768 blocks (32m x 24n), z = n0>>10 ----------------
// XCD-rectangle mapping: each XCD owns an 8m x 12n rectangle (5 MB working set).
__global__ __launch_bounds__(256, 2) void gemm_qkv128(
    const u16* __restrict__ xhat, const u16* __restrict__ WTcat,
    const float* __restrict__ bfold,
    float* __restrict__ kout, float* __restrict__ vout,
    u16* __restrict__ qbf, u16* __restrict__ kbf, u16* __restrict__ vTb)
{
  __shared__ u16 lds[4 * 128 * GBK];                // [buf][A/B], 64 KiB
  const int t = threadIdx.x;
  const int xcd = blockIdx.x & 7, l = blockIdx.x >> 3;  // l in [0,96)
  const int by = 8 * (xcd >> 1) + l / 12;
  const int bx = 12 * (xcd & 1) + l % 12;
  const int m0 = by * 128, n0 = bx * 128;

  f32x4 acc[4][4] = {};
  core128(xhat, WTcat, m0, n0, t, lds, acc);

  const int lane = t & 63, wave = t >> 6;
  const int wm = wave >> 1, wn = wave & 1;
  const int fr = lane & 15, hi = lane >> 4;
  const int z = n0 >> 10;
  const float* bias = bfold + z * E_DIM;
  const int rowb = hi * 4;
  #pragma unroll
  for (int i = 0; i < 4; ++i) {
    const int mbase = m0 + wm * 64 + i * 16 + rowb;
    #pragma unroll
    for (int j = 0; j < 4; ++j) {
      const int ng = n0 + wn * 64 + j * 16 + fr;
      const int ncol = ng & 1023;
      const float bval = bias[ncol];
      #pragma unroll
      for (int r = 0; r < 4; ++r) {
        const int m = mbase + r;
        const float val = acc[i][j][r] + bval;
        const int b = m >> 11, ltok = m & 2047, h = ncol >> 6, d = ncol & 63;
        const size_t bh = (size_t)(b * NH + h);
        if (z == 0) {
          qbf[((bh * L_SEQ + ltok) << 6) + d] = f2bf(val);
        } else if (z == 1) {
          kout[(bh * 64 + d) * L_SEQ + ltok] = val;
          kbf[((bh * L_SEQ + ltok) << 6) + d] = f2bf(val);
        } else {
          vout[(bh * L_SEQ + ltok) * 64 + d] = val;
          vTb[(bh * 64 + d) * L_SEQ + ltok] = f2bf(val);
        }
      }
    }
  }
}

// ---------------- final GEMM: out = what @ (g_o . Wo) + bfold_o + tokens; 256 blocks ----------------
__global__ __launch_bounds__(256, 2) void gemm_o128(
    const u16* __restrict__ A, const u16* __restrict__ BT, const float* __restrict__ bias,
    const float* __restrict__ tokens, float* __restrict__ out)
{
  __shared__ u16 lds[4 * 128 * GBK];
  const int t = threadIdx.x;
  const int xcd = blockIdx.x & 7, l = blockIdx.x >> 3;  // l in [0,32)
  const int by = 8 * (xcd >> 1) + (l >> 2);
  const int bx = 4 * (xcd & 1) + (l & 3);
  const int m0 = by * 128, n0 = bx * 128;

  f32x4 acc[4][4] = {};
  core128(A, BT, m0, n0, t, lds, acc);

  const int lane = t & 63, wave = t >> 6;
  const int wm = wave >> 1, wn = wave & 1;
  const int fr = lane & 15, hi = lane >> 4;
  const int rowb = hi * 4;
  #pragma unroll
  for (int i = 0; i < 4; ++i) {
    const int mbase = m0 + wm * 64 + i * 16 + rowb;
    #pragma unroll
    for (int j = 0; j < 4; ++j) {
      const int ncol = n0 + wn * 64 + j * 16 + fr;
      const float bval = bias[ncol];
      #pragma unroll
      for (int r = 0; r < 4; ++r) {
        const int m = mbase + r;
        out[(size_t)m * E_DIM + ncol] = acc[i][j][r] + bval + tokens[(size_t)m * E_DIM + ncol];
      }
    }
  }
}

// ---------------- MFMA flash attention, q-tile-paired (R8 structure) ----------------
// VALU diet: log2-domain softmax (exp2f = bare v_exp_f32); P pack by bf16 TRUNCATION
// (3 ops/pair vs ~8 RNE; P>=0, rel err <= 2^-8, slack 3.6x); defer-max THR=8 (T13).
__global__ __launch_bounds__(256) void attn_mfma(
    const u16* __restrict__ qbf, const u16* __restrict__ kbf,
    const u16* __restrict__ vTb, u16* __restrict__ wv)
{
  __shared__ u16 Klds[64][72];
  __shared__ u16 Vlds[64][72];
  __shared__ u16 Plds[4][16][72];
  const int t = threadIdx.x, lane = t & 63, wave = t >> 6;
  const int bi = blockIdx.x;
  const int bh = (bi & 7) + 8 * ((bi >> 3) & 3);   // b*NH + h, XCD-grouped
  const int pr = bi >> 5;                          // pair index 0..15
  const int fr = lane & 15, hi = lane >> 4;
  const u16* kbase = kbf + (size_t)bh * L_SEQ * 64;
  const u16* vbase = vTb + (size_t)bh * 64 * L_SEQ;
  const int b = bh >> 4, h = bh & 15;
  const float kSC2  = 0.125f * 1.44269504089f;     // score scale in log2 domain
  const float kMSK2 = -1803.2f;                    // -1249.875 * log2e

  #pragma unroll 1
  for (int half = 0; half < 2; ++half) {
    const int qt = half ? (31 - pr) : pr;
    const int q0w = qt * 64 + wave * 16;
    const int qg = q0w + fr;

    const u16* qrow = qbf + ((size_t)bh * L_SEQ + q0w + fr) * 64 + hi * 8;
    const bf16x8 qf0 = *reinterpret_cast<const bf16x8*>(qrow);
    const bf16x8 qf1 = *reinterpret_cast<const bf16x8*>(qrow + 32);

    f32x4 o[4] = {};
    float mrun = -3.0e38f, lrun = 0.f;             // mrun in log2 domain

    for (int tkv = 0; tkv <= qt; ++tkv) {
      const int j0 = tkv * 64;
      const bool diag = (tkv == qt);
      #pragma unroll
      for (int s = 0; s < 2; ++s) {
        const int seg = t + s * 256;
        const int r = seg >> 3, c8 = (seg & 7) * 8;
        *reinterpret_cast<uint4*>(&Klds[r][c8]) =
            *reinterpret_cast<const uint4*>(kbase + (size_t)(j0 + r) * 64 + c8);
        *reinterpret_cast<uint4*>(&Vlds[r][c8]) =
            *reinterpret_cast<const uint4*>(vbase + (size_t)r * L_SEQ + j0 + c8);
      }
      __syncthreads();

      f32x4 st[4] = {};
      __builtin_amdgcn_s_setprio(1);
      #pragma unroll
      for (int kt = 0; kt < 4; ++kt) {
        bf16x8 ka0 = *reinterpret_cast<const bf16x8*>(&Klds[kt*16 + fr][hi*8]);
        bf16x8 ka1 = *reinterpret_cast<const bf16x8*>(&Klds[kt*16 + fr][32 + hi*8]);
        st[kt] = __builtin_amdgcn_mfma_f32_16x16x32_bf16(ka0, qf0, st[kt], 0, 0, 0);
        st[kt] = __builtin_amdgcn_mfma_f32_16x16x32_bf16(ka1, qf1, st[kt], 0, 0, 0);
      }
      __builtin_amdgcn_s_setprio(0);

      float p[16];
      float pmax = -3.0e38f;
      #pragma unroll
      for (int kt = 0; kt < 4; ++kt)
        #pragma unroll
        for (int r = 0; r < 4; ++r) {
          const int key = j0 + kt*16 + hi*4 + r;
          const float v = st[kt][r] * kSC2 + ((diag && key > qg) ? kMSK2 : 0.f);
          p[kt*4 + r] = v;
          pmax = fmaxf(pmax, v);
        }
      pmax = fmaxf(pmax, __shfl_xor(pmax, 16));
      pmax = fmaxf(pmax, __shfl_xor(pmax, 32));
      // defer-max (T13): rescale only when some q-row's max grew > 8 (log2 units)
      if (!__all(pmax - mrun <= 8.f)) {
        const float mnew = fmaxf(mrun, pmax);
        const float alpha = exp2f(mrun - mnew);
        #pragma unroll
        for (int r = 0; r < 4; ++r) {
          const float ar = __shfl(alpha, hi*4 + r);
          o[0][r] *= ar; o[1][r] *= ar; o[2][r] *= ar; o[3][r] *= ar;
        }
        lrun *= alpha;
        mrun = mnew;
      }
      float lsum = 0.f;
      #pragma unroll
      for (int i = 0; i < 16; ++i) { p[i] = exp2f(p[i] - mrun); lsum += p[i]; }
      lsum += __shfl_xor(lsum, 16);
      lsum += __shfl_xor(lsum, 32);
      lrun += lsum;

      // P -> per-wave LDS via truncation pack (keys hi*4+0..3 per chunk)
      #pragma unroll
      for (int kt = 0; kt < 4; ++kt) {
        uint2 w2;
        w2.x = pktrunc(p[kt*4+0], p[kt*4+1]);
        w2.y = pktrunc(p[kt*4+2], p[kt*4+3]);
        *reinterpret_cast<uint2*>(&Plds[wave][fr][kt*16 + hi*4]) = w2;
      }

      const bf16x8 pf0 = *reinterpret_cast<const bf16x8*>(&Plds[wave][fr][hi*8]);
      const bf16x8 pf1 = *reinterpret_cast<const bf16x8*>(&Plds[wave][fr][32 + hi*8]);
      __builtin_amdgcn_s_setprio(1);
      #pragma unroll
      for (int dt = 0; dt < 4; ++dt) {
        bf16x8 vf0 = *reinterpret_cast<const bf16x8*>(&Vlds[dt*16 + fr][hi*8]);
        bf16x8 vf1 = *reinterpret_cast<const bf16x8*>(&Vlds[dt*16 + fr][32 + hi*8]);
        o[dt] = __builtin_amdgcn_mfma_f32_16x16x32_bf16(pf0, vf0, o[dt], 0, 0, 0);
        o[dt] = __builtin_amdgcn_mfma_f32_16x16x32_bf16(pf1, vf1, o[dt], 0, 0, 0);
      }
      __builtin_amdgcn_s_setprio(0);
      __syncthreads();
    }

    const float inv = 1.f / lrun;
    #pragma unroll
    for (int r = 0; r < 4; ++r) {
      const float ir = __shfl(inv, hi*4 + r);
      const int q = q0w + hi*4 + r;
      u16* dst = wv + (size_t)(b * L_SEQ + q) * E_DIM + h * 64 + fr;
      #pragma unroll
      for (int dt = 0; dt < 4; ++dt)
        dst[dt * 16] = f2bf(o[dt][r] * ir);
    }
  }
}

extern "C" void kernel_launch(void* const* d_in, const int* in_sizes, int n_in,
                              void* d_out, int out_size, void* d_ws, size_t ws_size,
                              hipStream_t stream) {
  (void)in_sizes; (void)n_in; (void)out_size; (void)ws_size;
  const float* tokens = (const float*)d_in[0];
  const float* ln_q_g = (const float*)d_in[1];
  const float* ln_q_b = (const float*)d_in[2];
  const float* Wq     = (const float*)d_in[3];
  const float* bq     = (const float*)d_in[4];
  const float* ln_k_g = (const float*)d_in[5];
  const float* ln_k_b = (const float*)d_in[6];
  const float* Wk     = (const float*)d_in[7];
  const float* bk     = (const float*)d_in[8];
  const float* ln_v_g = (const float*)d_in[9];
  const float* ln_v_b = (const float*)d_in[10];
  const float* Wv     = (const float*)d_in[11];
  const float* bv     = (const float*)d_in[12];
  const float* ln_o_g = (const float*)d_in[13];
  const float* ln_o_b = (const float*)d_in[14];
  const float* Wo     = (const float*)d_in[15];
  const float* bo     = (const float*)d_in[16];

  float* out  = (float*)d_out;            // (2,2048,1024)
  float* kout = out + 4194304;            // (2,16,64,2048)
  float* vout = kout + 4194304;           // (2,16,2048,64)

  char* w = (char*)d_ws;
  const size_t MB = (size_t)1 << 20;
  u16*   WTq   = (u16*)(w + 0 * MB);     // (g_q . Wq)^T — WTq/WTv/WTk contiguous = WTcat (3072 x 1024)
  u16*   WTv   = (u16*)(w + 2 * MB);
  u16*   WTk   = (u16*)(w + 4 * MB);
  u16*   WTo   = (u16*)(w + 6 * MB);     // (g_o . Wo)^T
  u16*   xhat  = (u16*)(w + 8 * MB);     // shared LN x-hat; REUSED as wvb after gemm_qkv
  u16*   qbf   = (u16*)(w + 16 * MB);    // q bf16 (N,H,L,64)
  u16*   kbf   = (u16*)(w + 24 * MB);    // k bf16 (N,H,L,64)
  u16*   vTb   = (u16*)(w + 32 * MB);    // v^T bf16 (N,H,64,L)
  u16*   what  = (u16*)(w + 40 * MB);    // LN x-hat of wv
  float* bfold = (float*)(w + 48 * MB);  // 4 x 1024 folded biases (q, k(Wv), v(Wk), o)
  u16*   wvb   = xhat;                   // attn out (N,L,E) — xhat dead after gemm_qkv

  transpose_all<<<dim3(32, 32, 4), 256, 0, stream>>>(
      Wq, Wv, Wk, Wo, ln_q_g, ln_v_g, ln_k_g, ln_o_g, WTq, WTv, WTk, WTo);
  bias_fold<<<dim3(32, 4), 256, 0, stream>>>(
      Wq, Wv, Wk, Wo, ln_q_b, ln_v_b, ln_k_b, ln_o_b, bq, bv, bk, bo, bfold);
  ln_hat_f32<<<M_ROWS, 256, 0, stream>>>(tokens, xhat);
  gemm_qkv128<<<768, 256, 0, stream>>>(xhat, WTq, bfold, kout, vout, qbf, kbf, vTb);
  attn_mfma<<<512, 256, 0, stream>>>(qbf, kbf, vTb, wvb);
  ln_hat_bf16<<<M_ROWS, 256, 0, stream>>>(wvb, what);
  gemm_o128<<<256, 256, 0, stream>>>(what, WTo, bfold + 3 * E_DIM, tokens, out);
}